// Round 6
// baseline (5205.599 us; speedup 1.0000x reference)
//
#include <hip/hip_runtime.h>
#include <hip/hip_fp16.h>
#include <stdint.h>
#include <stddef.h>

// DRNN (dilated 3-layer LSTM), B=128, T=1024, F=128, H=256, dil=[1,2,4].
//  - Input GEMMs hoisted out of recurrence (f16 MFMA 16x16x32), G in 67MB chunks.
//  - R9 = R8 with one fix: wave-1 G stager addressed Gbuf with GLOBAL t
//    (+t0*1024) but Gbuf is a 256-step chunk staged at LOCAL rows 0..255.
//    Chunks with t0>0 read past the staged data (into H0e) -> garbage gates in
//    5/7 recurrence dispatches. Fix: chunk-local addressing (match R7's cell).
//  - R8 design (unchanged): R3..R7 all pinned at ~2.2us/step regardless of
//    compute structure. Diagnosis: the spin-poll's atomic load is the youngest
//    VMEM op, so consuming it = s_waitcnt vmcnt(0) = drain of in-flight HBM
//    G-prefetch + store acks, EVERY retry, EVERY step (vmcnt in-order,
//    per-wave). Fix: wave specialization partitions per-wave vmcnt counters:
//      * wave 0: cell + publish + outputs. Gates/G read from LDS only.
//      * wave 1: MFMA + G stager (LDS double-buffer, depth-4 register ring,
//        static indexing via 4x-unrolled main loop).
//      * waves 2-3: gather. Poll 8 tagged words each (sentinel word first)
//        on a CLEAN vmcnt -> retries cost one L2 RTT, not a drain.
//    Kept verbatim from R7 (passed): MFMA fragment mapping, tagged-word
//    exchange {tag=t+1|f16x2} parity t&1, swizzled hbuf, raw lgkmcnt-only
//    barriers, k_gemm, prep.

typedef _Float16 f16;
typedef _Float16 v2h __attribute__((ext_vector_type(2)));
typedef _Float16 v8h __attribute__((ext_vector_type(8)));
typedef __fp16 h2_raw __attribute__((ext_vector_type(2)));
typedef __fp16 h8_raw __attribute__((ext_vector_type(8)));
typedef float v4f __attribute__((ext_vector_type(4)));
typedef unsigned long long u64;

#define DEVINL static __device__ __forceinline__

DEVINL float sigm(float x) { return 1.0f / (1.0f + __expf(-x)); }
DEVINL float tanh_(float x) {
  x = fminf(fmaxf(x, -15.0f), 15.0f);
  float e = __expf(-2.0f * x);
  return (1.0f - e) / (1.0f + e);
}
DEVINL v2h pack2(float a, float b) {
  return __builtin_bit_cast(v2h, __builtin_amdgcn_cvt_pkrtz(a, b));
}
DEVINL v4f mfma_16x16x32(v8h a, v8h b, v4f c) {
  return __builtin_amdgcn_mfma_f32_16x16x32_f16(__builtin_bit_cast(h8_raw, a),
                                                __builtin_bit_cast(h8_raw, b), c,
                                                0, 0, 0);
}

// Workgroup barrier WITHOUT vmcnt drain: LDS ordered (lgkmcnt(0)), global
// loads/stores stay in flight (compiler inserts counted vmcnt at use).
DEVINL void wg_barrier() {
  __builtin_amdgcn_sched_barrier(0);
  asm volatile("s_waitcnt lgkmcnt(0)" ::: "memory");
  __builtin_amdgcn_s_barrier();
  asm volatile("" ::: "memory");
  __builtin_amdgcn_sched_barrier(0);
}

// ---------------- prep ----------------

__global__ void k_cvt_x(const float2* __restrict__ src, v2h* __restrict__ dst, int n2) {
  int i = blockIdx.x * blockDim.x + threadIdx.x;
  int st = gridDim.x * blockDim.x;
  for (; i < n2; i += st) {
    float2 v = src[i];
    dst[i] = pack2(v.x, v.y);
  }
}

__global__ void k_prep_w(const float* __restrict__ wih0, const float* __restrict__ whh0,
                         const float* __restrict__ wih1, const float* __restrict__ whh1,
                         const float* __restrict__ wih2, const float* __restrict__ whh2,
                         const float* __restrict__ bi0, const float* __restrict__ bh0,
                         const float* __restrict__ bi1, const float* __restrict__ bh1,
                         const float* __restrict__ bi2, const float* __restrict__ bh2,
                         f16* wih0f, f16* whh0f, f16* wih1f, f16* whh1f,
                         f16* wih2f, f16* whh2f,
                         float* bias0, float* bias1, float* bias2) {
  int i = blockIdx.x * blockDim.x + threadIdx.x;  // grid covers 262144
  if (i < 131072) wih0f[i] = (f16)wih0[i];
  whh0f[i] = (f16)whh0[i];
  wih1f[i] = (f16)wih1[i];
  whh1f[i] = (f16)whh1[i];
  wih2f[i] = (f16)wih2[i];
  whh2f[i] = (f16)whh2[i];
  if (i < 1024) {
    bias0[i] = bi0[i] + bh0[i];
    bias1[i] = bi1[i] + bh1[i];
    bias2[i] = bi2[i] + bh2[i];
  }
}

// ---------------- input GEMM (unchanged) ----------------

template <int K>
__launch_bounds__(256)
__global__ void k_gemm(const f16* __restrict__ A, int Tb, int t0,
                       const f16* __restrict__ W, const float* __restrict__ bias,
                       f16* __restrict__ G) {
  constexpr int LDK = K + 8;
  __shared__ f16 As[64 * LDK];
  int b = blockIdx.x >> 2, tb = blockIdx.x & 3;
  const f16* Ablk = A + ((size_t)b * Tb + t0 + tb * 64) * K;
  int tid = threadIdx.x;

  constexpr int NV = 64 * K / 8;
  const uint4* src = (const uint4*)Ablk;
  for (int i = tid; i < NV; i += 256) {
    int e = i * 8;
    int r = e / K, c0 = e % K;
    *(uint4*)&As[r * LDK + c0] = src[i];
  }
  __syncthreads();

  int wave = tid >> 6, lane = tid & 63;
  int lm = lane & 15, lk = (lane >> 4) * 8;

  v8h af[K / 32];
#pragma unroll
  for (int kc = 0; kc < K / 32; ++kc)
    af[kc] = *(const v8h*)&As[(wave * 16 + lm) * LDK + kc * 32 + lk];

  size_t grow0 = (size_t)b * 256 + tb * 64 + wave * 16;
  for (int nt = 0; nt < 64; ++nt) {
    v4f acc = {0.0f, 0.0f, 0.0f, 0.0f};
    const f16* Wrow = W + (size_t)(nt * 16 + lm) * K + lk;
#pragma unroll
    for (int kc = 0; kc < K / 32; ++kc) {
      v8h bf = *(const v8h*)(Wrow + kc * 32);
      acc = mfma_16x16x32(af[kc], bf, acc);
    }
    float bv = bias[nt * 16 + lm];
#pragma unroll
    for (int r = 0; r < 4; ++r) {
      int m = (lane >> 4) * 4 + r;
      G[(grow0 + m) * 1024 + nt * 16 + lm] = (f16)(acc[r] + bv);
    }
  }
}

// ---------------- recurrence (R9: wave-specialized, chunk-local G) ----------------
// grid 256 x 256. g = blk & 15 (batches [g*8,g*8+8)), sub = blk >> 4,
// d0 = sub*16 (h-dims [d0,d0+16), gate cols {q*256+d0..+15}).
// P1 (all waves): MFMA gate q=wv; wave1 also stages G (LDS write + issue).
// P2: wave0 = cell+publish+outputs (LDS-only reads);
//     waves2-3 = poll 8 words each (clean vmcnt) + swizzled hbuf fill.

template <int LAYER>
__launch_bounds__(256)
__global__ void k_rec(const f16* __restrict__ G,   // chunk [128][256][1024] f16
                      const f16* __restrict__ Whh, // [1024][256] f16
                      int t0, int steps,           // steps == 256, t0 even
                      f16* __restrict__ Hout, float* __restrict__ y,
                      float* __restrict__ hstate, float* __restrict__ cstate,
                      u64* hxw) {
  int blk = blockIdx.x;
  int g = blk & 15, sub = blk >> 4;
  int d0 = sub * 16;
  int tid = threadIdx.x;
  int lane = tid & 63, wv = tid >> 6;
  int q = wv;                            // MFMA gate
  int arow = lane & 15, s4 = lane >> 4;  // MFMA A-row / k-subgroup

  // wave0 cell role: lane -> (batch bl0, word-pair wp)
  int bl0 = lane >> 3, wp = lane & 7;
  int b0 = g * 8 + bl0;

  // waves2-3 gather role: p128 -> (row pbl, source sub subp)
  int p128 = tid - 128;                  // valid for wv>=2
  int pbl = (p128 >> 4) & 7, subp = p128 & 15;

  // wave1 G-stager role: lane -> (batch bl1, gate qg, 8-col half h8)
  int bl1 = lane >> 3, qg = (lane & 7) >> 1, h8 = lane & 1;

  __shared__ __align__(16) f16 hbuf[16][256];   // 16B-chunk XOR swizzle (^row&7)
  __shared__ float gq[4][8][18];                // [gate][batch][dim], pad 2
  __shared__ __align__(16) f16 Gl[2][8 * 72];   // [par][bl*72 + q*16 + 2wp]

  // W_hh B-frags: wf[kt], lane holds Whh[q*256+d0+arow][kt*32 + s4*8 + j]
  v8h wf[8];
  {
    const v8h* wrow = (const v8h*)&Whh[(size_t)(q * 256 + d0 + arow) * 256];
#pragma unroll
    for (int kt = 0; kt < 8; ++kt) wf[kt] = wrow[kt * 4 + s4];
#pragma unroll
    for (int i = 0; i < 8; ++i) asm volatile("" : "+v"(wf[i]));
  }

  // ---- init hbuf / state ----
  float c0 = 0.f, c1 = 0.f, h0 = 0.f, h1 = 0.f;
  {
    uint4 z = {0u, 0u, 0u, 0u};
    *(uint4*)((char*)hbuf + 4096 + tid * 16) = z;  // rows 8-15: zero forever
    if (t0 == 0) {
      *(uint4*)((char*)hbuf + tid * 16) = z;
    } else {
      if (wv >= 2) {  // rows 0-7 from hstate, swizzled (same math as gather)
        const float4* hs =
            (const float4*)&hstate[(size_t)(g * 8 + pbl) * 256 + subp * 16];
        float4 a = hs[0], bq = hs[1], cc = hs[2], dd = hs[3];
        uint4 lo, hi;
        lo.x = __builtin_bit_cast(uint32_t, pack2(a.x, a.y));
        lo.y = __builtin_bit_cast(uint32_t, pack2(a.z, a.w));
        lo.z = __builtin_bit_cast(uint32_t, pack2(bq.x, bq.y));
        lo.w = __builtin_bit_cast(uint32_t, pack2(bq.z, bq.w));
        hi.x = __builtin_bit_cast(uint32_t, pack2(cc.x, cc.y));
        hi.y = __builtin_bit_cast(uint32_t, pack2(cc.z, cc.w));
        hi.z = __builtin_bit_cast(uint32_t, pack2(dd.x, dd.y));
        hi.w = __builtin_bit_cast(uint32_t, pack2(dd.z, dd.w));
        int c0i = (2 * subp) ^ (pbl & 7), c1i = (2 * subp + 1) ^ (pbl & 7);
        *(uint4*)((char*)hbuf + pbl * 512 + c0i * 16) = lo;
        *(uint4*)((char*)hbuf + pbl * 512 + c1i * 16) = hi;
      }
      if (wv == 0) {
        float2 cc = *(const float2*)&cstate[(size_t)b0 * 256 + d0 + 2 * wp];
        c0 = cc.x; c1 = cc.y;
        float2 hh = *(const float2*)&hstate[(size_t)b0 * 256 + d0 + 2 * wp];
        h0 = hh.x; h1 = hh.y;
      }
    }
  }

  u64* hx_g = hxw + (size_t)g * 2048;                      // [2][8][128] u64
  u64* pubp = hx_g + (size_t)bl0 * 128 + sub * 8 + wp;     // +pp*1024 (wave0)
  const u64* pollp = hx_g + (size_t)pbl * 128 + subp * 8;  // +pp*1024 (wv>=2)

  // wave1 G pipeline: depth-4 register ring, LDS double buffer.
  // NOTE: Gbuf is a 256-step CHUNK -> chunk-local rows (no t0 term). R8's bug.
  const f16* Gw = G + (size_t)(g * 8 + bl1) * 262144 + qg * 256 + d0 + h8 * 8;
  char* GlW = (char*)Gl + bl1 * 144 + qg * 32 + h8 * 16;
  uint4 g0r, g1r, g2r, g3r;
  if (wv == 1) {
    g0r = *(const uint4*)(Gw);
    g1r = *(const uint4*)(Gw + 1024);
    g2r = *(const uint4*)(Gw + 2048);
    g3r = *(const uint4*)(Gw + 3072);
    *(uint4*)(GlW) = g0r;  // Gl[0] <- local row 0
  }
  __syncthreads();
  if (wv == 1) g0r = *(const uint4*)(Gw + 4096);  // slot reuse: local row 4

  const char* gq0 = (const char*)gq;
  const char* Glb = (const char*)Gl;

#define CELL_AND_PUBLISH(J)                                                    \
  {                                                                            \
    float2 zi = *(const float2*)(gq0 + ((0 * 8 + bl0) * 18 + 2 * wp) * 4);     \
    float2 zf = *(const float2*)(gq0 + ((1 * 8 + bl0) * 18 + 2 * wp) * 4);     \
    float2 zg = *(const float2*)(gq0 + ((2 * 8 + bl0) * 18 + 2 * wp) * 4);     \
    float2 zo = *(const float2*)(gq0 + ((3 * 8 + bl0) * 18 + 2 * wp) * 4);     \
    const char* glr = Glb + ((J) & 1) * 1152 + bl0 * 144 + wp * 4;             \
    v2h G0 = *(const v2h*)(glr);                                               \
    v2h G1 = *(const v2h*)(glr + 32);                                          \
    v2h G2 = *(const v2h*)(glr + 64);                                          \
    v2h G3 = *(const v2h*)(glr + 96);                                          \
    float i0 = sigm(zi.x + (float)G0[0]), i1 = sigm(zi.y + (float)G0[1]);      \
    float f0 = sigm(zf.x + (float)G1[0]), f1 = sigm(zf.y + (float)G1[1]);      \
    float gg0 = tanh_(zg.x + (float)G2[0]), gg1 = tanh_(zg.y + (float)G2[1]);  \
    float o0 = sigm(zo.x + (float)G3[0]), o1 = sigm(zo.y + (float)G3[1]);      \
    c0 = f0 * c0 + i0 * gg0;                                                   \
    c1 = f1 * c1 + i1 * gg1;                                                   \
    h0 = o0 * tanh_(c0);                                                       \
    h1 = o1 * tanh_(c1);                                                       \
    uint32_t hp = __builtin_bit_cast(uint32_t, pack2(h0, h1));                 \
    __hip_atomic_store(pubp + (size_t)pp * 1024,                               \
                       ((u64)(uint32_t)(t + 1) << 32) | (u64)hp,               \
                       __ATOMIC_RELAXED, __HIP_MEMORY_SCOPE_AGENT);            \
    if (LAYER == 0) {                                                          \
      if ((t & 1) == 0) {                                                      \
        v2h hr; hr[0] = (f16)h0; hr[1] = (f16)h1;                              \
        *(uint32_t*)&Hout[((size_t)b0 * 512 + (t >> 1)) * 256 + d0 + 2 * wp] = \
            __builtin_bit_cast(uint32_t, hr);                                  \
      }                                                                        \
    } else if (LAYER == 1) {                                                   \
      if ((t & 1) == 0) {                                                      \
        v2h hr; hr[0] = (f16)h0; hr[1] = (f16)h1;                              \
        *(uint32_t*)&Hout[((size_t)b0 * 256 + (t >> 1)) * 256 + d0 + 2 * wp] = \
            __builtin_bit_cast(uint32_t, hr);                                  \
      }                                                                        \
    } else {                                                                   \
      size_t base = ((size_t)b0 * 1024 + (size_t)t * 4) * 256 + d0 + 2 * wp;   \
      float2 hv; hv.x = h0; hv.y = h1;                                         \
      *(float2*)&y[base] = hv;                                                 \
      *(float2*)&y[base + 256] = hv;                                           \
      *(float2*)&y[base + 512] = hv;                                           \
      *(float2*)&y[base + 768] = hv;                                           \
    }                                                                          \
  }

#define STEP(J, GWR, GLD)                                                      \
  {                                                                            \
    const int t = t0 + s + (J);                                                \
    const int pp = (t + 1) & 1;                                                \
    /* ---- P1: MFMA (all waves) + G staging (wave1) ---- */                   \
    v4f acc0 = {0.f, 0.f, 0.f, 0.f}, acc1 = {0.f, 0.f, 0.f, 0.f};              \
    _Pragma("unroll") for (int kt = 0; kt < 8; kt += 2) {                      \
      v8h a0 = *(const v8h*)((const char*)hbuf + arow * 512 +                  \
                             (((kt * 4 + s4) ^ (arow & 7)) * 16));             \
      acc0 = mfma_16x16x32(a0, wf[kt], acc0);                                  \
      v8h a1 = *(const v8h*)((const char*)hbuf + arow * 512 +                  \
                             ((((kt + 1) * 4 + s4) ^ (arow & 7)) * 16));       \
      acc1 = mfma_16x16x32(a1, wf[kt + 1], acc1);                              \
    }                                                                          \
    if (lane < 32) {                                                           \
      int r0 = s4 * 4;                                                         \
      _Pragma("unroll") for (int r = 0; r < 4; ++r)                            \
        gq[q][r0 + r][arow] = acc0[r] + acc1[r];                               \
    }                                                                          \
    if (wv == 1) {                                                             \
      if (s + (J) + 1 < steps)                                                 \
        *(uint4*)(GlW + (((J) + 1) & 1) * 1152) = GWR;                         \
      if (s + (J) + 4 < steps)                                                 \
        GLD = *(const uint4*)(Gw + ((size_t)(s + (J) + 4) << 10));             \
    }                                                                          \
    wg_barrier(); /* BAR1 */                                                   \
    /* ---- P2: roles ---- */                                                  \
    if (wv == 0) {                                                             \
      CELL_AND_PUBLISH(J)                                                      \
    } else if (wv >= 2) {                                                      \
      if (s + (J) + 1 < steps) {                                               \
        const u64* pb = pollp + (size_t)pp * 1024;                             \
        int tau = t + 1;                                                       \
        u64 w0 = __hip_atomic_load(pb, __ATOMIC_RELAXED,                       \
                                   __HIP_MEMORY_SCOPE_AGENT);                  \
        while ((int)(w0 >> 32) < tau)                                          \
          w0 = __hip_atomic_load(pb, __ATOMIC_RELAXED,                         \
                                 __HIP_MEMORY_SCOPE_AGENT);                    \
        u64 w1, w2, w3, w4, w5, w6, w7;                                        \
        for (;;) {                                                             \
          w1 = __hip_atomic_load(pb + 1, __ATOMIC_RELAXED,                     \
                                 __HIP_MEMORY_SCOPE_AGENT);                    \
          w2 = __hip_atomic_load(pb + 2, __ATOMIC_RELAXED,                     \
                                 __HIP_MEMORY_SCOPE_AGENT);                    \
          w3 = __hip_atomic_load(pb + 3, __ATOMIC_RELAXED,                     \
                                 __HIP_MEMORY_SCOPE_AGENT);                    \
          w4 = __hip_atomic_load(pb + 4, __ATOMIC_RELAXED,                     \
                                 __HIP_MEMORY_SCOPE_AGENT);                    \
          w5 = __hip_atomic_load(pb + 5, __ATOMIC_RELAXED,                     \
                                 __HIP_MEMORY_SCOPE_AGENT);                    \
          w6 = __hip_atomic_load(pb + 6, __ATOMIC_RELAXED,                     \
                                 __HIP_MEMORY_SCOPE_AGENT);                    \
          w7 = __hip_atomic_load(pb + 7, __ATOMIC_RELAXED,                     \
                                 __HIP_MEMORY_SCOPE_AGENT);                    \
          if ((int)(w1 >> 32) >= tau && (int)(w2 >> 32) >= tau &&              \
              (int)(w3 >> 32) >= tau && (int)(w4 >> 32) >= tau &&              \
              (int)(w5 >> 32) >= tau && (int)(w6 >> 32) >= tau &&              \
              (int)(w7 >> 32) >= tau)                                          \
            break;                                                             \
        }                                                                      \
        uint4 lo, hi;                                                          \
        lo.x = (uint32_t)w0; lo.y = (uint32_t)w1;                              \
        lo.z = (uint32_t)w2; lo.w = (uint32_t)w3;                              \
        hi.x = (uint32_t)w4; hi.y = (uint32_t)w5;                              \
        hi.z = (uint32_t)w6; hi.w = (uint32_t)w7;                              \
        int c0i = (2 * subp) ^ (pbl & 7), c1i = (2 * subp + 1) ^ (pbl & 7);    \
        *(uint4*)((char*)hbuf + pbl * 512 + c0i * 16) = lo;                    \
        *(uint4*)((char*)hbuf + pbl * 512 + c1i * 16) = hi;                    \
      }                                                                        \
    }                                                                          \
    wg_barrier(); /* BAR2 */                                                   \
  }

  for (int s = 0; s < steps; s += 4) {
    STEP(0, g1r, g0r)
    STEP(1, g2r, g1r)
    STEP(2, g3r, g2r)
    STEP(3, g0r, g3r)
  }
#undef STEP
#undef CELL_AND_PUBLISH

  if (wv == 0) {  // chunk state for own dims (all subs cover all 256 dims)
    size_t sb = (size_t)b0 * 256 + d0 + 2 * wp;
    float2 hv; hv.x = h0; hv.y = h1;
    float2 cv; cv.x = c0; cv.y = c1;
    *(float2*)&hstate[sb] = hv;
    *(float2*)&cstate[sb] = cv;
  }
}

// ---------------- orchestration ----------------

extern "C" void kernel_launch(void* const* d_in, const int* in_sizes, int n_in,
                              void* d_out, int out_size, void* d_ws, size_t ws_size,
                              hipStream_t stream) {
  const float* x = (const float*)d_in[0];
  const float* wih[3] = {(const float*)d_in[1], (const float*)d_in[5], (const float*)d_in[9]};
  const float* whh[3] = {(const float*)d_in[2], (const float*)d_in[6], (const float*)d_in[10]};
  const float* bi[3] = {(const float*)d_in[3], (const float*)d_in[7], (const float*)d_in[11]};
  const float* bh[3] = {(const float*)d_in[4], (const float*)d_in[8], (const float*)d_in[12]};
  float* y = (float*)d_out;

  // workspace layout (~155 MB total)
  char* p = (char*)d_ws;
  f16* Xf = (f16*)p;        p += (size_t)16777216 * 2;        // 33.5 MB
  f16* Wih0f = (f16*)p;     p += (size_t)131072 * 2;
  f16* Whh0f = (f16*)p;     p += (size_t)262144 * 2;
  f16* Wih1f = (f16*)p;     p += (size_t)262144 * 2;
  f16* Whh1f = (f16*)p;     p += (size_t)262144 * 2;
  f16* Wih2f = (f16*)p;     p += (size_t)262144 * 2;
  f16* Whh2f = (f16*)p;     p += (size_t)262144 * 2;
  float* bias0 = (float*)p; p += 4096;
  float* bias1 = (float*)p; p += 4096;
  float* bias2 = (float*)p; p += 4096;
  f16* Gbuf = (f16*)p;      p += (size_t)32768 * 1024 * 2;    // 67 MB chunk
  f16* H0e = (f16*)p;       p += (size_t)128 * 512 * 256 * 2; // 33.5 MB
  f16* H1q = (f16*)p;       p += (size_t)128 * 256 * 256 * 2; // 16.8 MB
  float* hstate = (float*)p; p += (size_t)128 * 256 * 4;
  float* cstate = (float*)p; p += (size_t)128 * 256 * 4;
  u64* hxw0 = (u64*)p;      p += (size_t)16 * 2 * 1024 * 8;   // 256 KB tagged words
  u64* hxw1 = (u64*)p;      p += (size_t)16 * 2 * 1024 * 8;
  u64* hxw2 = (u64*)p;      p += (size_t)16 * 2 * 1024 * 8;

  // prep
  k_cvt_x<<<4096, 256, 0, stream>>>((const float2*)x, (v2h*)Xf, 8388608);
  k_prep_w<<<1024, 256, 0, stream>>>(wih[0], whh[0], wih[1], whh[1], wih[2], whh[2],
                                     bi[0], bh[0], bi[1], bh[1], bi[2], bh[2],
                                     Wih0f, Whh0f, Wih1f, Whh1f, Wih2f, Whh2f,
                                     bias0, bias1, bias2);

  // layer 0: 4 chunks of 256 steps
  for (int c = 0; c < 4; ++c) {
    k_gemm<128><<<512, 256, 0, stream>>>(Xf, 1024, c * 256, Wih0f, bias0, Gbuf);
    k_rec<0><<<256, 256, 0, stream>>>(Gbuf, Whh0f, c * 256, 256, H0e, nullptr,
                                      hstate, cstate, hxw0);
  }
  // layer 1: 2 chunks of 256 steps (inputs = h0 at even t)
  for (int c = 0; c < 2; ++c) {
    k_gemm<256><<<512, 256, 0, stream>>>(H0e, 512, c * 256, Wih1f, bias1, Gbuf);
    k_rec<1><<<256, 256, 0, stream>>>(Gbuf, Whh1f, c * 256, 256, H1q, nullptr,
                                      hstate, cstate, hxw1);
  }
  // layer 2: 1 chunk of 256 steps (inputs = h1 at t%4==0); writes y with 4x broadcast
  k_gemm<256><<<512, 256, 0, stream>>>(H1q, 256, 0, Wih2f, bias2, Gbuf);
  k_rec<2><<<256, 256, 0, stream>>>(Gbuf, Whh2f, 0, 256, nullptr, y,
                                    hstate, cstate, hxw2);
}